// Round 4
// baseline (366.743 us; speedup 1.0000x reference)
//
#include <hip/hip_runtime.h>

// Embedding gather, fully fused: out[pos,:] = W[:, x[pos]]
//   x: [16384] int32, W: [1024, 50257] f32 row-major, out: [16384, 1024] f32
//
// R3 lessons: 64KB LDS tile -> 2 blocks/CU -> latency/convoy-bound (1.3 TB/s,
// VALUBusy 4.6%); single-block prepass ~30us serialized. LLC absorbs ~half of
// W (FETCH 103MB), so HBM traffic is already near floor — the win is
// concurrency, not bytes.
//
// R4: ONE kernel, no prepass, no workspace. Block (dchunk,w) stages the
// [64 dims x 64 ids] tile (16.6KB -> 7 blocks/CU with the 4KB match list),
// then scans x itself (x is 64KB, L2-resident on every XCD; 3152 blocks x
// 64KB = 197MB of L2 reads ~ 6us aggregate). Matches are appended to an LDS
// ring list via LDS atomics and flushed every 1024 scanned elements with
// coalesced 256B wave-stores (d = lane sweeps dims). Ring + flush-per-1024
// is correct for ANY token distribution (max appends per cycle == CAP).
// Grid (x=dchunk 16, y=w 786): consecutive-w blocks of a dchunk are 16 apart
// in linear id -> same XCD (id%8) -> boundary-line L2 reuse.

#define DIMS    1024
#define TOKENS  50257
#define WSIZE   64
#define NW      ((TOKENS + WSIZE - 1) / WSIZE)   // 786
#define CAP     1024                             // ring capacity (pow2)
#define CHUNK   CAP                              // x elems per flush cycle

__global__ __launch_bounds__(256, 7) void embed_fused(
    const int* __restrict__ x, int n,
    const float* __restrict__ W,
    float* __restrict__ out)
{
    __shared__ float tile[WSIZE * 65];   // [dim_row][id_col], pitch 65 (2-way max = free)
    __shared__ int   lst[CAP];           // packed (pos<<6)|col
    __shared__ int   cnt;

    const int dchunk = blockIdx.x;       // 0..15
    const int w      = blockIdx.y;       // 0..785
    const int dbase  = dchunk * WSIZE;
    const int id0    = w * WSIZE;
    const int t      = threadIdx.x;

    if (t == 0) cnt = 0;

    // ---- stage W[dbase:+64, id0:+64] -> LDS (coalesced 256B/wave rows) ----
    {
        const int c  = t & 63;
        const int rq = t >> 6;                        // 0..3
        const int id = id0 + c;
        const bool ok = (id < TOKENS);                // last window partial
        const float* p = W + (size_t)(dbase + rq) * TOKENS + (ok ? id : id0);
        #pragma unroll
        for (int i = 0; i < 16; ++i)
            tile[(i * 4 + rq) * 65 + c] = ok ? p[(size_t)(i * 4) * TOKENS] : 0.0f;
    }
    __syncthreads();                                  // tile + cnt=0 visible

    // ---- scan x, append matches, flush coalesced ----
    const int d  = t & 63;                            // lane sweeps 64 dims
    const int jo = t >> 6;                            // 4 tokens / flush iter
    float* const obase = out + dbase + d;

    const int n4 = n >> 2;                            // n == 16384, 4-divisible
    const int4* __restrict__ x4 = (const int4*)x;
    const int nchunks = (n4 + (CHUNK / 4) - 1) / (CHUNK / 4);

    int base = 0;
    for (int ck = 0; ck < nchunks; ++ck) {
        const int i4 = ck * (CHUNK / 4) + t;          // 256 thr x int4 = 1024 elems
        if (i4 < n4) {
            const int4 v = x4[i4];
            const int pos = i4 * 4;
            const unsigned c0 = (unsigned)(v.x - id0);
            const unsigned c1 = (unsigned)(v.y - id0);
            const unsigned c2 = (unsigned)(v.z - id0);
            const unsigned c3 = (unsigned)(v.w - id0);
            if (c0 < WSIZE) { int k = atomicAdd(&cnt, 1); lst[k & (CAP-1)] = ((pos    ) << 6) | c0; }
            if (c1 < WSIZE) { int k = atomicAdd(&cnt, 1); lst[k & (CAP-1)] = ((pos + 1) << 6) | c1; }
            if (c2 < WSIZE) { int k = atomicAdd(&cnt, 1); lst[k & (CAP-1)] = ((pos + 2) << 6) | c2; }
            if (c3 < WSIZE) { int k = atomicAdd(&cnt, 1); lst[k & (CAP-1)] = ((pos + 3) << 6) | c3; }
        }
        __syncthreads();                              // appends visible
        const int tot = cnt;
        for (int j = base + jo; j < tot; j += 4) {
            const int pk  = lst[j & (CAP-1)];         // wave-uniform -> broadcast
            const int col = pk & 63;
            const int pos = pk >> 6;
            obase[(size_t)pos * DIMS] = tile[d * 65 + col];   // 256B wave-store
        }
        base = tot;
        __syncthreads();                              // flush done before ring reuse
    }
}

extern "C" void kernel_launch(void* const* d_in, const int* in_sizes, int n_in,
                              void* d_out, int out_size, void* d_ws, size_t ws_size,
                              hipStream_t stream) {
    const int*   x = (const int*)d_in[0];     // [16384]
    const float* W = (const float*)d_in[1];   // [1024, 50257]
    float*     out = (float*)d_out;

    const int n = in_sizes[0];                // 16384

    dim3 grid(DIMS / WSIZE, NW);              // (16, 786)
    embed_fused<<<grid, 256, 0, stream>>>(x, n, W, out);
}